// Round 6
// baseline (7153.085 us; speedup 1.0000x reference)
//
#include <hip/hip_runtime.h>
#include <math.h>

#define B_  2048
#define S_  32
#define T_  32
#define D_  128
#define H_  256
#define G3  768
#define VT_ 256
#define BOW_ 1
#define NB  8

typedef __attribute__((ext_vector_type(8))) short short8;
typedef __attribute__((ext_vector_type(4))) float f32x4;
typedef __attribute__((ext_vector_type(8))) unsigned short us8;
typedef unsigned short u16;

__device__ inline u16 f2bf(float x) {
  union { float f; unsigned u; } v; v.f = x;
  unsigned r = v.u + 0x7FFFu + ((v.u >> 16) & 1u);
  return (u16)(r >> 16);
}
__device__ inline float bf2f(u16 b) {
  union { unsigned u; float f; } v; v.u = ((unsigned)b) << 16; return v.f;
}
__device__ inline int swz(int r) { return ((r ^ (r >> 3)) & 7) << 3; }
__device__ inline float sigm(float x) { return 1.f / (1.f + expf(-x)); }

// ---------------- weight transpose + split ----------------
struct TMat { const float* src; u16* dhi; u16* dlo; int R; int C; int tile0; };
struct TPack { TMat m[10]; };

__global__ __launch_bounds__(256)
void wsplit_t(TPack P) {
  int bx = blockIdx.x;
  TMat M = P.m[0];
  #pragma unroll
  for (int i = 1; i < 10; i++) if (bx >= P.m[i].tile0) M = P.m[i];
  int ti = bx - M.tile0;
  int tilesR = M.R >> 6;
  int rt = ti % tilesR, ct = ti / tilesR;
  int r0 = rt * 64, c0 = ct * 64;
  __shared__ float ts[64][65];
  int tid = threadIdx.x;
  int cx = tid & 63, ry = tid >> 6;
  #pragma unroll
  for (int i = 0; i < 16; i++) {
    int r = ry * 16 + i;
    ts[r][cx] = M.src[(size_t)(r0 + r) * M.C + c0 + cx];
  }
  __syncthreads();
  int rx = tid & 63, cy = tid >> 6;
  #pragma unroll
  for (int i = 0; i < 16; i++) {
    int cc = cy * 16 + i;
    float v = ts[rx][cc];
    u16 hi = f2bf(v);
    size_t o = (size_t)(c0 + cc) * M.R + r0 + rx;
    M.dhi[o] = hi;
    M.dlo[o] = f2bf(v - bf2f(hi));
  }
}

__global__ __launch_bounds__(256)
void esplit(const float* a, const float* b, u16* ah, u16* al, u16* bh, u16* bl, int n) {
  int i = blockIdx.x * 256 + threadIdx.x;
  if (i >= 2 * n) return;
  const float* s = (i < n) ? a : b;
  u16* dh = (i < n) ? ah : bh;
  u16* dl = (i < n) ? al : bl;
  int j = (i < n) ? i : i - n;
  float v = s[j];
  u16 hi = f2bf(v);
  dh[j] = hi; dl[j] = f2bf(v - bf2f(hi));
}

// ---------------- plane GEMM (round-4 version) ----------------
struct PLeg {
  const u16* Ahi; const u16* Alo; int lda;
  const u16* Bthi; const u16* Btlo; int ldb;
  const float* bias; void* C; int ldc; int cmode;  // 0=f32, 1=bf16, 2=logits-layout
  int M, N, K;
};

__global__ __launch_bounds__(256)
void gemm_pl(PLeg l0, PLeg l1) {
  PLeg L = blockIdx.z ? l1 : l0;
  int n0 = blockIdx.x * 128; if (n0 >= L.N) return;
  int m0 = blockIdx.y * 128; if (m0 >= L.M) return;
  __shared__ u16 As[128 * 64];
  __shared__ u16 Bs[128 * 64];
  int tid = threadIdx.x;
  int lane = tid & 63, wv = tid >> 6;
  int wr = (wv >> 1) * 64, wc = (wv & 1) * 64;
  int fr = lane & 15, fk = (lane >> 4) * 8;
  f32x4 acc[4][4];
  #pragma unroll
  for (int m = 0; m < 4; m++)
    #pragma unroll
    for (int n = 0; n < 4; n++) acc[m][n] = (f32x4){0.f, 0.f, 0.f, 0.f};

  int s_row = tid >> 1, s_part = tid & 1;

  for (int k0 = 0; k0 < L.K; k0 += 32) {
    if (k0) __syncthreads();
    int swA = swz(s_row);
    {
      const u16* src = (s_part ? L.Alo : L.Ahi) + (size_t)(m0 + s_row) * L.lda + k0;
      #pragma unroll
      for (int q = 0; q < 4; q++)
        *(us8*)&As[(s_row * 64 + s_part * 32 + q * 8) ^ swA] = *(const us8*)(src + q * 8);
    }
    {
      const u16* src = (s_part ? L.Btlo : L.Bthi) + (size_t)(n0 + s_row) * L.ldb + k0;
      #pragma unroll
      for (int q = 0; q < 4; q++)
        *(us8*)&Bs[(s_row * 64 + s_part * 32 + q * 8) ^ swA] = *(const us8*)(src + q * 8);
    }
    __syncthreads();
    short8 bhi[4], blo[4];
    #pragma unroll
    for (int n = 0; n < 4; n++) {
      int cc = wc + n * 16 + fr; int sw = swz(cc);
      bhi[n] = *(const short8*)&Bs[(cc * 64 + fk) ^ sw];
      blo[n] = *(const short8*)&Bs[(cc * 64 + 32 + fk) ^ sw];
    }
    #pragma unroll
    for (int m = 0; m < 4; m++) {
      int r = wr + m * 16 + fr; int sw = swz(r);
      short8 ahi = *(const short8*)&As[(r * 64 + fk) ^ sw];
      short8 alo = *(const short8*)&As[(r * 64 + 32 + fk) ^ sw];
      #pragma unroll
      for (int n = 0; n < 4; n++) {
        acc[m][n] = __builtin_amdgcn_mfma_f32_16x16x32_bf16(ahi, bhi[n], acc[m][n], 0, 0, 0);
        acc[m][n] = __builtin_amdgcn_mfma_f32_16x16x32_bf16(ahi, blo[n], acc[m][n], 0, 0, 0);
        acc[m][n] = __builtin_amdgcn_mfma_f32_16x16x32_bf16(alo, bhi[n], acc[m][n], 0, 0, 0);
      }
    }
  }
  int rbase = (lane >> 4) * 4;
  #pragma unroll
  for (int m = 0; m < 4; m++)
    #pragma unroll
    for (int rr = 0; rr < 4; rr++) {
      int row = m0 + wr + m * 16 + rbase + rr;
      #pragma unroll
      for (int n = 0; n < 4; n++) {
        int col = n0 + wc + n * 16 + fr;
        float v = acc[m][n][rr];
        if (L.bias) v += L.bias[col];
        if (L.cmode == 0)      ((float*)L.C)[(size_t)row * L.ldc + col] = v;
        else if (L.cmode == 1) ((u16*)L.C)[(size_t)row * L.ldc + col] = f2bf(v);
        else {
          size_t o = (((size_t)(row & (B_ - 1))) * T_ + (row >> 11)) * VT_ + col;
          ((float*)L.C)[o] = v;
        }
      }
    }
}

// ---------------- fused GRU step (LDS A-panel, gx via table) ----------------
struct GruDesc {
  const u16 *a0H, *a0L;       // h planes (lda 256)
  const u16 *a1H, *a1L;       // dec only: ctx planes (lda 256)
  const u16 *b0H, *b0L;       // U^T planes [768][256]
  const u16 *b1H, *b1L;       // dec only: Wc^T planes [768][256]
  const float *gxT;           // [vocab(256)][768] precomputed x@W
  const float *bias0, *bias1;
  const float *hold;          // f32 hold (null -> holdH/L planes)
  const u16 *holdH, *holdL;
  float *hnew;
  u16 *hh, *hl;
  u16 *ssH, *ssL;             // enc: pre-sliced to pos
  const int *ids;
  int ssmode;                 // 0 none, 1 store, 2 finalize(add)
  int sidx, rev;
};

template<int MODE>   // 0 = encoder (K=256), 1 = decoder (K=512)
__global__ __launch_bounds__(256)
void gru_step(GruDesc d0, GruDesc d1) {
  GruDesc D = blockIdx.z ? d1 : d0;
  constexpr int KT  = MODE ? 512 : 256;
  constexpr int KT8 = KT / 8;
  constexpr int MF  = MODE ? 1 : 2;
  constexpr int NST = KT / 32;
  __shared__ __align__(16) u16 As[2 * 32 * KT];

  int m0 = blockIdx.y * 32;
  int tid = threadIdx.x;
  int lane = tid & 63, wv = tid >> 6;
  int fr = lane & 15, kq = lane >> 4;
  int jn, rb0;
  if (MODE == 0) { jn = blockIdx.x * 64 + wv * 16 + fr; rb0 = 0; }
  else           { jn = blockIdx.x * 32 + (wv & 1) * 16 + fr; rb0 = (wv >> 1) * 16; }

  // ---- stage A panel (32 rows x KT, hi+lo planes) ----
  constexpr int PER_T = (2 * 32 * KT8) / 256;
  #pragma unroll
  for (int i = 0; i < PER_T; i++) {
    int s = tid + i * 256;
    int p = s / (32 * KT8);
    int rem = s - p * (32 * KT8);
    int row = rem / KT8;
    int kb = rem - row * KT8;
    int k = kb * 8;
    const u16* src;
    if (MODE == 0) {
      src = (p ? D.a0L : D.a0H) + (size_t)(m0 + row) * 256 + k;
    } else {
      src = (k < 256) ? (p ? D.a0L : D.a0H) + (size_t)(m0 + row) * 256 + k
                      : (p ? D.a1L : D.a1H) + (size_t)(m0 + row) * 256 + (k - 256);
    }
    *(us8*)&As[(s ^ (row & 7)) * 8] = *(const us8*)src;
  }
  __syncthreads();

  // acc strips: 0=z 1=r 2=hc 3=xc(dec only)
  f32x4 acc[4][MF];
  #pragma unroll
  for (int a = 0; a < 4; a++)
    #pragma unroll
    for (int mf = 0; mf < MF; mf++) acc[a][mf] = (f32x4){0.f, 0.f, 0.f, 0.f};

  #pragma unroll
  for (int i = 0; i < NST; i++) {
    const u16 *BH, *BL; int bk, ai2;
    if (MODE == 0)    { BH = D.b0H; BL = D.b0L; bk = i * 32; ai2 = 2; }
    else if (i < 8)   { BH = D.b0H; BL = D.b0L; bk = i * 32; ai2 = 2; }
    else              { BH = D.b1H; BL = D.b1L; bk = (i - 8) * 32; ai2 = 3; }
    short8 ah[MF], al[MF];
    #pragma unroll
    for (int mf = 0; mf < MF; mf++) {
      int rp = rb0 + mf * 16 + fr;
      int kb = i * 4 + kq;
      ah[mf] = *(const short8*)&As[((rp * KT8 + kb) ^ (fr & 7)) * 8];
      al[mf] = *(const short8*)&As[((32 * KT8 + rp * KT8 + kb) ^ (fr & 7)) * 8];
    }
    #pragma unroll
    for (int st = 0; st < 3; st++) {
      size_t ro = (size_t)(st * 256 + jn) * 256 + bk + kq * 8;
      short8 bh = *(const short8*)(BH + ro);
      short8 bl = *(const short8*)(BL + ro);
      int ai = (st < 2) ? st : ai2;
      #pragma unroll
      for (int mf = 0; mf < MF; mf++) {
        acc[ai][mf] = __builtin_amdgcn_mfma_f32_16x16x32_bf16(ah[mf], bh, acc[ai][mf], 0, 0, 0);
        acc[ai][mf] = __builtin_amdgcn_mfma_f32_16x16x32_bf16(ah[mf], bl, acc[ai][mf], 0, 0, 0);
        acc[ai][mf] = __builtin_amdgcn_mfma_f32_16x16x32_bf16(al[mf], bh, acc[ai][mf], 0, 0, 0);
      }
    }
  }

  // ---- gate epilogue ----
  int rbase = kq * 4;
  int j = jn;
  float b0z = D.bias0[j],       b1z = D.bias1[j];
  float b0r = D.bias0[256 + j], b1r = D.bias1[256 + j];
  float b0c = D.bias0[512 + j], b1c = D.bias1[512 + j];
  #pragma unroll
  for (int mf = 0; mf < MF; mf++)
    #pragma unroll
    for (int rr = 0; rr < 4; rr++) {
      int b = m0 + rb0 + mf * 16 + rbase + rr;
      size_t o = (size_t)b * H_ + j;
      int id;
      if (MODE == 0) id = D.ids[b * S_ + (D.rev ? (S_ - 1 - D.sidx) : D.sidx)];
      else           id = (D.sidx == 0) ? BOW_ : D.ids[b * T_ + D.sidx - 1];
      const float* T = D.gxT + (size_t)id * G3;
      float z = sigm(acc[0][mf][rr] + T[j] + b0z + b1z);
      float r = sigm(acc[1][mf][rr] + T[256 + j] + b0r + b1r);
      float xc = T[512 + j] + b0c + (MODE ? acc[3][mf][rr] : 0.f);
      float c = tanhf(xc + r * (acc[2][mf][rr] + b1c));
      float hprev = D.hold ? D.hold[o] : (bf2f(D.holdH[o]) + bf2f(D.holdL[o]));
      float hn = z * hprev + (1.f - z) * c;
      D.hnew[o] = hn;
      u16 hi = f2bf(hn);
      D.hh[o] = hi; D.hl[o] = f2bf(hn - bf2f(hi));
      if (MODE == 0) {
        if (D.ssmode == 1) {
          D.ssH[o] = hi; D.ssL[o] = f2bf(hn - bf2f(hi));
        } else if (D.ssmode == 2) {
          float v = bf2f(D.ssH[o]) + bf2f(D.ssL[o]) + hn;
          u16 vh = f2bf(v);
          D.ssH[o] = vh; D.ssL[o] = f2bf(v - bf2f(vh));
        }
      }
    }
}

// ---------------- fused LP + attention (NB batch rows per block) ----------------
__global__ __launch_bounds__(256)
void lp_attend(const u16* __restrict__ hH, const u16* __restrict__ hL,
               const float* __restrict__ stW, const float* __restrict__ stb,
               const u16* __restrict__ projbf, const u16* __restrict__ ssH,
               const float* __restrict__ att_v,
               u16* __restrict__ ctxh, u16* __restrict__ ctxl) {
  int b0 = blockIdx.x * NB;
  int tid = threadIdx.x;
  int lane = tid & 63, wv = tid >> 6;
  __shared__ float hsh[NB][H_];
  __shared__ float ps[NB][H_];
  __shared__ float ews[NB][S_];
  #pragma unroll
  for (int bb = 0; bb < NB; bb++) {
    size_t o = (size_t)(b0 + bb) * H_ + tid;
    hsh[bb][tid] = bf2f(hH[o]) + bf2f(hL[o]);
  }
  __syncthreads();
  // p[bb][tid] = h[bb] @ att_st_W[:, tid] + bias
  float p[NB];
  float pb = stb[tid];
  #pragma unroll
  for (int bb = 0; bb < NB; bb++) p[bb] = pb;
  for (int k = 0; k < H_; k++) {
    float w = stW[(size_t)k * H_ + tid];
    #pragma unroll
    for (int bb = 0; bb < NB; bb++) p[bb] = fmaf(hsh[bb][k], w, p[bb]);
  }
  #pragma unroll
  for (int bb = 0; bb < NB; bb++) ps[bb][tid] = p[bb];
  __syncthreads();
  // scores: wave wv handles bb = wv*2, wv*2+1
  float vq[4];
  #pragma unroll
  for (int q = 0; q < 4; q++) vq[q] = att_v[q * 64 + lane];
  #pragma unroll
  for (int u = 0; u < 2; u++) {
    int bb = wv * 2 + u;
    float pq[4];
    #pragma unroll
    for (int q = 0; q < 4; q++) pq[q] = ps[bb][q * 64 + lane];
    for (int s = 0; s < S_; s++) {
      const u16* pr = projbf + ((size_t)s * B_ + b0 + bb) * H_;
      float part = 0.f;
      #pragma unroll
      for (int q = 0; q < 4; q++)
        part += tanhf(bf2f(pr[q * 64 + lane]) + pq[q]) * vq[q];
      #pragma unroll
      for (int off = 32; off; off >>= 1) part += __shfl_xor(part, off);
      if (lane == 0) ews[bb][s] = part;
    }
  }
  __syncthreads();
  if (tid < NB) {
    float m = -1e30f;
    #pragma unroll
    for (int s = 0; s < S_; s++) m = fmaxf(m, ews[tid][s]);
    float ex[S_]; float den = 0.f;
    #pragma unroll
    for (int s = 0; s < S_; s++) { ex[s] = expf(ews[tid][s] - m); den += ex[s]; }
    float inv = 1.f / den;
    #pragma unroll
    for (int s = 0; s < S_; s++) ews[tid][s] = ex[s] * inv;
  }
  __syncthreads();
  #pragma unroll
  for (int bb = 0; bb < NB; bb++) {
    float acc = 0.f;
    #pragma unroll
    for (int s = 0; s < S_; s++)
      acc = fmaf(ews[bb][s], bf2f(ssH[((size_t)s * B_ + b0 + bb) * H_ + tid]), acc);
    u16 hi = f2bf(acc);
    size_t o = (size_t)(b0 + bb) * H_ + tid;
    ctxh[o] = hi; ctxl[o] = f2bf(acc - bf2f(hi));
  }
}

// ---------------- host ----------------
extern "C" void kernel_launch(void* const* d_in, const int* in_sizes, int n_in,
                              void* d_out, int out_size, void* d_ws, size_t ws_size,
                              hipStream_t stream) {
  const float* src_emb   = (const float*)d_in[0];
  const float* tgt_emb   = (const float*)d_in[1];
  const float* enc_f_W   = (const float*)d_in[2];
  const float* enc_f_U   = (const float*)d_in[3];
  const float* enc_f_b   = (const float*)d_in[4];
  const float* enc_b_W   = (const float*)d_in[5];
  const float* enc_b_U   = (const float*)d_in[6];
  const float* enc_b_b   = (const float*)d_in[7];
  const float* dec_W     = (const float*)d_in[8];
  const float* dec_U     = (const float*)d_in[9];
  const float* dec_b     = (const float*)d_in[10];
  const float* out_W     = (const float*)d_in[11];
  const float* out_b     = (const float*)d_in[12];
  const float* att_src_W = (const float*)d_in[13];
  const float* att_src_b = (const float*)d_in[14];
  const float* att_st_W  = (const float*)d_in[15];
  const float* att_st_b  = (const float*)d_in[16];
  const float* att_v     = (const float*)d_in[17];
  const int* source_ids  = (const int*)d_in[19];
  const int* target_ids  = (const int*)d_in[20];
  float* out = (float*)d_out;

  char* base = (char*)d_ws;
  size_t off = 0;
  auto allocB = [&](size_t bytes) { void* p = base + off; off = (off + bytes + 255) & ~255UL; return p; };
  const size_t BH = (size_t)B_ * H_;

  u16* ssH    = (u16*)allocB((size_t)S_ * BH * 2);
  u16* ssL    = (u16*)allocB((size_t)S_ * BH * 2);
  u16* projbf = (u16*)allocB((size_t)S_ * BH * 2);
  u16* ctxh = (u16*)allocB(BH * 2);
  u16* ctxl = (u16*)allocB(BH * 2);

  float* encF0 = (float*)allocB(2 * BH * 4);
  u16*  encPl0 = (u16*)allocB(4 * BH * 2);
  float* encF1 = (float*)allocB(2 * BH * 4);
  u16*  encPl1 = (u16*)allocB(4 * BH * 2);
  float* encF[2][2]  = { { encF0, encF0 + BH }, { encF1, encF1 + BH } };
  u16*  encH[2][2]   = { { encPl0, encPl0 + 2 * BH }, { encPl1, encPl1 + 2 * BH } };
  u16*  encL[2][2]   = { { encPl0 + BH, encPl0 + 3 * BH }, { encPl1 + BH, encPl1 + 3 * BH } };

  float* hDecF[2] = { (float*)allocB(BH * 4), (float*)allocB(BH * 4) };
  u16* hAllH = (u16*)allocB((size_t)T_ * BH * 2);
  u16* hAllL = (u16*)allocB((size_t)T_ * BH * 2);

  auto planes2 = [&](size_t n, u16*& h, u16*& l) { h = (u16*)allocB(n * 2); l = (u16*)allocB(n * 2); };
  u16 *UtFh,*UtFl,*UtBh,*UtBl,*WtFh,*WtFl,*WtBh,*WtBl;
  u16 *dUth,*dUtl,*dWcth,*dWctl,*dWxth,*dWxtl;
  u16 *oWth,*oWtl,*aSrth,*aSrtl;
  u16 *sEh,*sEl,*tEh,*tEl;
  planes2((size_t)G3*H_, UtFh, UtFl);   planes2((size_t)G3*H_, UtBh, UtBl);
  planes2((size_t)G3*D_, WtFh, WtFl);   planes2((size_t)G3*D_, WtBh, WtBl);
  planes2((size_t)G3*H_, dUth, dUtl);   planes2((size_t)G3*H_, dWcth, dWctl);
  planes2((size_t)G3*D_, dWxth, dWxtl);
  planes2((size_t)H_*VT_, oWth, oWtl);
  planes2((size_t)H_*H_, aSrth, aSrtl);
  planes2((size_t)VT_*D_, sEh, sEl);    planes2((size_t)VT_*D_, tEh, tEl);
  float* Tf = (float*)allocB((size_t)VT_ * G3 * 4);
  float* Tb = (float*)allocB((size_t)VT_ * G3 * 4);
  float* Td = (float*)allocB((size_t)VT_ * G3 * 4);

  TPack P;
  P.m[0] = { enc_f_U,          UtFh, UtFl, 256, 768, 0   };
  P.m[1] = { enc_b_U,          UtBh, UtBl, 256, 768, 48  };
  P.m[2] = { dec_U,            dUth, dUtl, 256, 768, 96  };
  P.m[3] = { dec_W + 128 * G3, dWcth, dWctl, 256, 768, 144 };
  P.m[4] = { enc_f_W,          WtFh, WtFl, 128, 768, 192 };
  P.m[5] = { enc_b_W,          WtBh, WtBl, 128, 768, 216 };
  P.m[6] = { dec_W,            dWxth, dWxtl, 128, 768, 240 };
  P.m[7] = { out_W,            oWth, oWtl, 256, 256, 264 };
  P.m[8] = { att_src_W,        aSrth, aSrtl, 256, 256, 280 };
  P.m[9] = { att_src_W,        aSrth, aSrtl, 256, 256, 1 << 30 };
  wsplit_t<<<296, 256, 0, stream>>>(P);
  esplit<<<(2 * VT_ * D_ + 255) / 256, 256, 0, stream>>>(src_emb, tgt_emb, sEh, sEl, tEh, tEl, VT_ * D_);

  // ---- gx tables: emb @ W (split-bf16 3-pass, f32 out) ----
  {
    PLeg tf = { sEh, sEl, D_, WtFh, WtFl, D_, nullptr, Tf, G3, 0, VT_, G3, D_ };
    PLeg tb = { sEh, sEl, D_, WtBh, WtBl, D_, nullptr, Tb, G3, 0, VT_, G3, D_ };
    gemm_pl<<<dim3(6, 2, 2), 256, 0, stream>>>(tf, tb);
    PLeg td = { tEh, tEl, D_, dWxth, dWxtl, D_, nullptr, Td, G3, 0, VT_, G3, D_ };
    gemm_pl<<<dim3(6, 2, 1), 256, 0, stream>>>(td, td);
  }

  hipMemsetAsync(encF0, 0, 2 * BH * 4, stream);
  hipMemsetAsync(encPl0, 0, 4 * BH * 2, stream);

  // ---- encoder ----
  for (int s = 0; s < S_; s++) {
    int p = s & 1;
    GruDesc dd[2];
    for (int d = 0; d < 2; d++) {
      GruDesc& D = dd[d];
      D.a0H = encH[p][d]; D.a0L = encL[p][d];
      D.a1H = nullptr; D.a1L = nullptr;
      D.b0H = d ? UtBh : UtFh; D.b0L = d ? UtBl : UtFl;
      D.b1H = nullptr; D.b1L = nullptr;
      D.gxT = d ? Tb : Tf;
      D.bias0 = d ? enc_b_b : enc_f_b;
      D.bias1 = (d ? enc_b_b : enc_f_b) + G3;
      D.hold = encF[p][d]; D.holdH = nullptr; D.holdL = nullptr;
      D.hnew = encF[p ^ 1][d];
      D.hh = encH[p ^ 1][d]; D.hl = encL[p ^ 1][d];
      int pos = d ? (S_ - 1 - s) : s;
      D.ssH = ssH + (size_t)pos * BH; D.ssL = ssL + (size_t)pos * BH;
      D.ids = source_ids;
      D.ssmode = (s < S_ / 2) ? 1 : 2;
      D.sidx = s; D.rev = d;
    }
    gru_step<0><<<dim3(4, 64, 2), 256, 0, stream>>>(dd[0], dd[1]);
  }

  // ---- proj (bf16) ----
  {
    PLeg proj = { ssH, ssL, H_, aSrth, aSrtl, H_, att_src_b, projbf, H_, 1, S_ * B_, H_, H_ };
    gemm_pl<<<dim3(2, 512, 1), 256, 0, stream>>>(proj, proj);
  }
  // ---- initial attention (h0 = ss[0] planes) ----
  lp_attend<<<B_ / NB, 256, 0, stream>>>(ssH, ssL, att_st_W, att_st_b,
                                         projbf, ssH, att_v, ctxh, ctxl);

  // ---- decoder ----
  for (int t = 0; t < T_; t++) {
    int p = t & 1;
    GruDesc D = {};
    D.a0H = t ? hAllH + (size_t)(t - 1) * BH : ssH;
    D.a0L = t ? hAllL + (size_t)(t - 1) * BH : ssL;
    D.a1H = ctxh; D.a1L = ctxl;
    D.b0H = dUth;  D.b0L = dUtl;
    D.b1H = dWcth; D.b1L = dWctl;
    D.gxT = Td;
    D.bias0 = dec_b; D.bias1 = dec_b + G3;
    if (t == 0) { D.hold = nullptr; D.holdH = ssH; D.holdL = ssL; }
    else        { D.hold = hDecF[p]; D.holdH = nullptr; D.holdL = nullptr; }
    D.hnew = hDecF[p ^ 1];
    D.hh = hAllH + (size_t)t * BH; D.hl = hAllL + (size_t)t * BH;
    D.ssH = nullptr; D.ssL = nullptr;
    D.ids = target_ids;
    D.ssmode = 0; D.sidx = t; D.rev = 0;
    gru_step<1><<<dim3(8, 64, 1), 256, 0, stream>>>(D, D);

    if (t < T_ - 1)
      lp_attend<<<B_ / NB, 256, 0, stream>>>(hAllH + (size_t)t * BH, hAllL + (size_t)t * BH,
                                             att_st_W, att_st_b,
                                             projbf, ssH, att_v, ctxh, ctxl);
  }

  // ---- batched logits ----
  {
    PLeg LO = { hAllH, hAllL, H_, oWth, oWtl, H_, out_b, out, 0, 2, T_ * B_, VT_, H_ };
    gemm_pl<<<dim3(2, 512, 1), 256, 0, stream>>>(LO, LO);
  }
}

// Round 7
// 3603.518 us; speedup vs baseline: 1.9850x; 1.9850x over previous
//
#include <hip/hip_runtime.h>
#include <math.h>

#define B_  2048
#define S_  32
#define T_  32
#define D_  128
#define H_  256
#define G3  768
#define VT_ 256
#define BOW_ 1

typedef __attribute__((ext_vector_type(8))) short short8;
typedef __attribute__((ext_vector_type(4))) float f32x4;
typedef __attribute__((ext_vector_type(8))) unsigned short us8;
typedef unsigned short u16;

__device__ inline u16 f2bf(float x) {
  union { float f; unsigned u; } v; v.f = x;
  unsigned r = v.u + 0x7FFFu + ((v.u >> 16) & 1u);
  return (u16)(r >> 16);
}
__device__ inline float bf2f(u16 b) {
  union { unsigned u; float f; } v; v.u = ((unsigned)b) << 16; return v.f;
}
__device__ inline int swz(int r) { return ((r ^ (r >> 3)) & 7) << 3; }
__device__ inline float sigm(float x) { return 1.f / (1.f + expf(-x)); }

// ---------------- weight transpose + split ----------------
struct TMat { const float* src; u16* dhi; u16* dlo; int R; int C; int tile0; };
struct TPack { TMat m[10]; };

__global__ __launch_bounds__(256)
void wsplit_t(TPack P) {
  int bx = blockIdx.x;
  TMat M = P.m[0];
  #pragma unroll
  for (int i = 1; i < 10; i++) if (bx >= P.m[i].tile0) M = P.m[i];
  int ti = bx - M.tile0;
  int tilesR = M.R >> 6;
  int rt = ti % tilesR, ct = ti / tilesR;
  int r0 = rt * 64, c0 = ct * 64;
  __shared__ float ts[64][65];
  int tid = threadIdx.x;
  int cx = tid & 63, ry = tid >> 6;
  #pragma unroll
  for (int i = 0; i < 16; i++) {
    int r = ry * 16 + i;
    ts[r][cx] = M.src[(size_t)(r0 + r) * M.C + c0 + cx];
  }
  __syncthreads();
  int rx = tid & 63, cy = tid >> 6;
  #pragma unroll
  for (int i = 0; i < 16; i++) {
    int cc = cy * 16 + i;
    float v = ts[rx][cc];
    u16 hi = f2bf(v);
    size_t o = (size_t)(c0 + cc) * M.R + r0 + rx;
    M.dhi[o] = hi;
    M.dlo[o] = f2bf(v - bf2f(hi));
  }
}

__global__ __launch_bounds__(256)
void esplit(const float* a, const float* b, u16* ah, u16* al, u16* bh, u16* bl, int n) {
  int i = blockIdx.x * 256 + threadIdx.x;
  if (i >= 2 * n) return;
  const float* s = (i < n) ? a : b;
  u16* dh = (i < n) ? ah : bh;
  u16* dl = (i < n) ? al : bl;
  int j = (i < n) ? i : i - n;
  float v = s[j];
  u16 hi = f2bf(v);
  dh[j] = hi; dl[j] = f2bf(v - bf2f(hi));
}

// ---------------- plane GEMM ----------------
struct PLeg {
  const u16* Ahi; const u16* Alo; int lda;
  const u16* Bthi; const u16* Btlo; int ldb;
  const float* bias; void* C; int ldc; int cmode;  // 0=f32, 1=bf16, 2=logits-layout
  int M, N, K;
};

__global__ __launch_bounds__(256)
void gemm_pl(PLeg l0, PLeg l1) {
  PLeg L = blockIdx.z ? l1 : l0;
  int n0 = blockIdx.x * 128; if (n0 >= L.N) return;
  int m0 = blockIdx.y * 128; if (m0 >= L.M) return;
  __shared__ u16 As[128 * 64];
  __shared__ u16 Bs[128 * 64];
  int tid = threadIdx.x;
  int lane = tid & 63, wv = tid >> 6;
  int wr = (wv >> 1) * 64, wc = (wv & 1) * 64;
  int fr = lane & 15, fk = (lane >> 4) * 8;
  f32x4 acc[4][4];
  #pragma unroll
  for (int m = 0; m < 4; m++)
    #pragma unroll
    for (int n = 0; n < 4; n++) acc[m][n] = (f32x4){0.f, 0.f, 0.f, 0.f};

  int s_row = tid >> 1, s_part = tid & 1;

  for (int k0 = 0; k0 < L.K; k0 += 32) {
    if (k0) __syncthreads();
    int swA = swz(s_row);
    {
      const u16* src = (s_part ? L.Alo : L.Ahi) + (size_t)(m0 + s_row) * L.lda + k0;
      #pragma unroll
      for (int q = 0; q < 4; q++)
        *(us8*)&As[(s_row * 64 + s_part * 32 + q * 8) ^ swA] = *(const us8*)(src + q * 8);
    }
    {
      const u16* src = (s_part ? L.Btlo : L.Bthi) + (size_t)(n0 + s_row) * L.ldb + k0;
      #pragma unroll
      for (int q = 0; q < 4; q++)
        *(us8*)&Bs[(s_row * 64 + s_part * 32 + q * 8) ^ swA] = *(const us8*)(src + q * 8);
    }
    __syncthreads();
    short8 bhi[4], blo[4];
    #pragma unroll
    for (int n = 0; n < 4; n++) {
      int cc = wc + n * 16 + fr; int sw = swz(cc);
      bhi[n] = *(const short8*)&Bs[(cc * 64 + fk) ^ sw];
      blo[n] = *(const short8*)&Bs[(cc * 64 + 32 + fk) ^ sw];
    }
    #pragma unroll
    for (int m = 0; m < 4; m++) {
      int r = wr + m * 16 + fr; int sw = swz(r);
      short8 ahi = *(const short8*)&As[(r * 64 + fk) ^ sw];
      short8 alo = *(const short8*)&As[(r * 64 + 32 + fk) ^ sw];
      #pragma unroll
      for (int n = 0; n < 4; n++) {
        acc[m][n] = __builtin_amdgcn_mfma_f32_16x16x32_bf16(ahi, bhi[n], acc[m][n], 0, 0, 0);
        acc[m][n] = __builtin_amdgcn_mfma_f32_16x16x32_bf16(ahi, blo[n], acc[m][n], 0, 0, 0);
        acc[m][n] = __builtin_amdgcn_mfma_f32_16x16x32_bf16(alo, bhi[n], acc[m][n], 0, 0, 0);
      }
    }
  }
  int rbase = (lane >> 4) * 4;
  #pragma unroll
  for (int m = 0; m < 4; m++)
    #pragma unroll
    for (int rr = 0; rr < 4; rr++) {
      int row = m0 + wr + m * 16 + rbase + rr;
      #pragma unroll
      for (int n = 0; n < 4; n++) {
        int col = n0 + wc + n * 16 + fr;
        float v = acc[m][n][rr];
        if (L.bias) v += L.bias[col];
        if (L.cmode == 0)      ((float*)L.C)[(size_t)row * L.ldc + col] = v;
        else if (L.cmode == 1) ((u16*)L.C)[(size_t)row * L.ldc + col] = f2bf(v);
        else {
          size_t o = (((size_t)(row & (B_ - 1))) * T_ + (row >> 11)) * VT_ + col;
          ((float*)L.C)[o] = v;
        }
      }
    }
}

// ---------------- fused GRU step (LDS A-panel, gx via table) ----------------
struct GruDesc {
  const u16 *a0H, *a0L;       // h planes (lda 256)
  const u16 *a1H, *a1L;       // dec only: ctx planes (lda 256)
  const u16 *b0H, *b0L;       // U^T planes [768][256]
  const u16 *b1H, *b1L;       // dec only: Wc^T planes [768][256]
  const float *gxT;           // [vocab(256)][768] precomputed x@W
  const float *bias0, *bias1;
  const float *hold;          // f32 hold (null -> holdH/L planes)
  const u16 *holdH, *holdL;
  float *hnew;
  u16 *hh, *hl;
  u16 *ssH, *ssL;             // enc: pre-sliced to pos
  const int *ids;
  int ssmode;                 // 0 none, 1 store, 2 finalize(add)
  int sidx, rev;
};

template<int MODE>   // 0 = encoder (K=256), 1 = decoder (K=512)
__global__ __launch_bounds__(256)
void gru_step(GruDesc d0, GruDesc d1) {
  GruDesc D = blockIdx.z ? d1 : d0;
  constexpr int KT  = MODE ? 512 : 256;
  constexpr int KT8 = KT / 8;
  constexpr int MF  = MODE ? 1 : 2;
  constexpr int NST = KT / 32;
  __shared__ __align__(16) u16 As[2 * 32 * KT];

  int m0 = blockIdx.y * 32;
  int tid = threadIdx.x;
  int lane = tid & 63, wv = tid >> 6;
  int fr = lane & 15, kq = lane >> 4;
  int jn, rb0;
  if (MODE == 0) { jn = blockIdx.x * 64 + wv * 16 + fr; rb0 = 0; }
  else           { jn = blockIdx.x * 32 + (wv & 1) * 16 + fr; rb0 = (wv >> 1) * 16; }

  // ---- stage A panel (32 rows x KT, hi+lo planes) ----
  constexpr int PER_T = (2 * 32 * KT8) / 256;
  #pragma unroll
  for (int i = 0; i < PER_T; i++) {
    int s = tid + i * 256;
    int p = s / (32 * KT8);
    int rem = s - p * (32 * KT8);
    int row = rem / KT8;
    int kb = rem - row * KT8;
    int k = kb * 8;
    const u16* src;
    if (MODE == 0) {
      src = (p ? D.a0L : D.a0H) + (size_t)(m0 + row) * 256 + k;
    } else {
      src = (k < 256) ? (p ? D.a0L : D.a0H) + (size_t)(m0 + row) * 256 + k
                      : (p ? D.a1L : D.a1H) + (size_t)(m0 + row) * 256 + (k - 256);
    }
    *(us8*)&As[(s ^ (row & 7)) * 8] = *(const us8*)src;
  }
  __syncthreads();

  // acc strips: 0=z 1=r 2=hc 3=xc(dec only)
  f32x4 acc[4][MF];
  #pragma unroll
  for (int a = 0; a < 4; a++)
    #pragma unroll
    for (int mf = 0; mf < MF; mf++) acc[a][mf] = (f32x4){0.f, 0.f, 0.f, 0.f};

  #pragma unroll
  for (int i = 0; i < NST; i++) {
    const u16 *BH, *BL; int bk, ai2;
    if (MODE == 0)    { BH = D.b0H; BL = D.b0L; bk = i * 32; ai2 = 2; }
    else if (i < 8)   { BH = D.b0H; BL = D.b0L; bk = i * 32; ai2 = 2; }
    else              { BH = D.b1H; BL = D.b1L; bk = (i - 8) * 32; ai2 = 3; }
    short8 ah[MF], al[MF];
    #pragma unroll
    for (int mf = 0; mf < MF; mf++) {
      int rp = rb0 + mf * 16 + fr;
      int kb = i * 4 + kq;
      ah[mf] = *(const short8*)&As[((rp * KT8 + kb) ^ (fr & 7)) * 8];
      al[mf] = *(const short8*)&As[((32 * KT8 + rp * KT8 + kb) ^ (fr & 7)) * 8];
    }
    #pragma unroll
    for (int st = 0; st < 3; st++) {
      size_t ro = (size_t)(st * 256 + jn) * 256 + bk + kq * 8;
      short8 bh = *(const short8*)(BH + ro);
      short8 bl = *(const short8*)(BL + ro);
      int ai = (st < 2) ? st : ai2;
      #pragma unroll
      for (int mf = 0; mf < MF; mf++) {
        acc[ai][mf] = __builtin_amdgcn_mfma_f32_16x16x32_bf16(ah[mf], bh, acc[ai][mf], 0, 0, 0);
        acc[ai][mf] = __builtin_amdgcn_mfma_f32_16x16x32_bf16(ah[mf], bl, acc[ai][mf], 0, 0, 0);
        acc[ai][mf] = __builtin_amdgcn_mfma_f32_16x16x32_bf16(al[mf], bh, acc[ai][mf], 0, 0, 0);
      }
    }
  }

  // ---- gate epilogue ----
  int rbase = kq * 4;
  int j = jn;
  float b0z = D.bias0[j],       b1z = D.bias1[j];
  float b0r = D.bias0[256 + j], b1r = D.bias1[256 + j];
  float b0c = D.bias0[512 + j], b1c = D.bias1[512 + j];
  #pragma unroll
  for (int mf = 0; mf < MF; mf++)
    #pragma unroll
    for (int rr = 0; rr < 4; rr++) {
      int b = m0 + rb0 + mf * 16 + rbase + rr;
      size_t o = (size_t)b * H_ + j;
      int id;
      if (MODE == 0) id = D.ids[b * S_ + (D.rev ? (S_ - 1 - D.sidx) : D.sidx)];
      else           id = (D.sidx == 0) ? BOW_ : D.ids[b * T_ + D.sidx - 1];
      const float* T = D.gxT + (size_t)id * G3;
      float z = sigm(acc[0][mf][rr] + T[j] + b0z + b1z);
      float r = sigm(acc[1][mf][rr] + T[256 + j] + b0r + b1r);
      float xc = T[512 + j] + b0c + (MODE ? acc[3][mf][rr] : 0.f);
      float c = tanhf(xc + r * (acc[2][mf][rr] + b1c));
      float hprev = D.hold ? D.hold[o] : (bf2f(D.holdH[o]) + bf2f(D.holdL[o]));
      float hn = z * hprev + (1.f - z) * c;
      D.hnew[o] = hn;
      u16 hi = f2bf(hn);
      D.hh[o] = hi; D.hl[o] = f2bf(hn - bf2f(hi));
      if (MODE == 0) {
        if (D.ssmode == 1) {
          D.ssH[o] = hi; D.ssL[o] = f2bf(hn - bf2f(hi));
        } else if (D.ssmode == 2) {
          float v = bf2f(D.ssH[o]) + bf2f(D.ssL[o]) + hn;
          u16 vh = f2bf(v);
          D.ssH[o] = vh; D.ssL[o] = f2bf(v - bf2f(vh));
        }
      }
    }
}

// ---------------- attention (1 block per batch row, batched loads) ----------------
__global__ __launch_bounds__(256)
void attend_k(const u16* __restrict__ projbf, const u16* __restrict__ ssH,
              const float* __restrict__ p, const float* __restrict__ att_v,
              u16* __restrict__ ctxh, u16* __restrict__ ctxl) {
  int b = blockIdx.x;
  int tid = threadIdx.x;
  int lane = tid & 63;
  int wv = tid >> 6;
  __shared__ float e_s[S_];
  __shared__ float w_s[S_];
  float pq[4], vq[4];
  #pragma unroll
  for (int q = 0; q < 4; q++) {
    pq[q] = p[(size_t)b * H_ + q * 64 + lane];
    vq[q] = att_v[q * 64 + lane];
  }
  float pv[8][4];
  #pragma unroll
  for (int i = 0; i < 8; i++) {
    const u16* pr = projbf + ((size_t)(wv * 8 + i) * B_ + b) * H_;
    #pragma unroll
    for (int q = 0; q < 4; q++) pv[i][q] = bf2f(pr[q * 64 + lane]);
  }
  u16 sv[S_];
  #pragma unroll
  for (int s = 0; s < S_; s++) sv[s] = ssH[((size_t)s * B_ + b) * H_ + tid];

  #pragma unroll
  for (int i = 0; i < 8; i++) {
    float part = 0.f;
    #pragma unroll
    for (int q = 0; q < 4; q++)
      part += tanhf(pv[i][q] + pq[q]) * vq[q];
    #pragma unroll
    for (int off = 32; off; off >>= 1)
      part += __shfl_xor(part, off);
    if (lane == 0) e_s[wv * 8 + i] = part;
  }
  __syncthreads();
  float m = -1e30f;
  #pragma unroll
  for (int s = 0; s < S_; s++) m = fmaxf(m, e_s[s]);
  float den = 0.f;
  #pragma unroll
  for (int s = 0; s < S_; s++) den += expf(e_s[s] - m);
  if (tid < S_) w_s[tid] = expf(e_s[tid] - m) / den;
  __syncthreads();
  float acc = 0.f;
  #pragma unroll
  for (int s = 0; s < S_; s++)
    acc = fmaf(w_s[s], bf2f(sv[s]), acc);
  u16 hi = f2bf(acc);
  size_t o = (size_t)b * H_ + tid;
  ctxh[o] = hi; ctxl[o] = f2bf(acc - bf2f(hi));
}

// ---------------- host ----------------
extern "C" void kernel_launch(void* const* d_in, const int* in_sizes, int n_in,
                              void* d_out, int out_size, void* d_ws, size_t ws_size,
                              hipStream_t stream) {
  const float* src_emb   = (const float*)d_in[0];
  const float* tgt_emb   = (const float*)d_in[1];
  const float* enc_f_W   = (const float*)d_in[2];
  const float* enc_f_U   = (const float*)d_in[3];
  const float* enc_f_b   = (const float*)d_in[4];
  const float* enc_b_W   = (const float*)d_in[5];
  const float* enc_b_U   = (const float*)d_in[6];
  const float* enc_b_b   = (const float*)d_in[7];
  const float* dec_W     = (const float*)d_in[8];
  const float* dec_U     = (const float*)d_in[9];
  const float* dec_b     = (const float*)d_in[10];
  const float* out_W     = (const float*)d_in[11];
  const float* out_b     = (const float*)d_in[12];
  const float* att_src_W = (const float*)d_in[13];
  const float* att_src_b = (const float*)d_in[14];
  const float* att_st_W  = (const float*)d_in[15];
  const float* att_st_b  = (const float*)d_in[16];
  const float* att_v     = (const float*)d_in[17];
  const int* source_ids  = (const int*)d_in[19];
  const int* target_ids  = (const int*)d_in[20];
  float* out = (float*)d_out;

  char* base = (char*)d_ws;
  size_t off = 0;
  auto allocB = [&](size_t bytes) { void* p = base + off; off = (off + bytes + 255) & ~255UL; return p; };
  const size_t BH = (size_t)B_ * H_;

  u16* ssH    = (u16*)allocB((size_t)S_ * BH * 2);
  u16* ssL    = (u16*)allocB((size_t)S_ * BH * 2);
  u16* projbf = (u16*)allocB((size_t)S_ * BH * 2);
  float* pbuf = (float*)allocB(BH * 4);
  u16* ctxh = (u16*)allocB(BH * 2);
  u16* ctxl = (u16*)allocB(BH * 2);

  float* encF0 = (float*)allocB(2 * BH * 4);
  u16*  encPl0 = (u16*)allocB(4 * BH * 2);
  float* encF1 = (float*)allocB(2 * BH * 4);
  u16*  encPl1 = (u16*)allocB(4 * BH * 2);
  float* encF[2][2]  = { { encF0, encF0 + BH }, { encF1, encF1 + BH } };
  u16*  encH[2][2]   = { { encPl0, encPl0 + 2 * BH }, { encPl1, encPl1 + 2 * BH } };
  u16*  encL[2][2]   = { { encPl0 + BH, encPl0 + 3 * BH }, { encPl1 + BH, encPl1 + 3 * BH } };

  float* hDecF[2] = { (float*)allocB(BH * 4), (float*)allocB(BH * 4) };
  u16* hAllH = (u16*)allocB((size_t)T_ * BH * 2);
  u16* hAllL = (u16*)allocB((size_t)T_ * BH * 2);

  auto planes2 = [&](size_t n, u16*& h, u16*& l) { h = (u16*)allocB(n * 2); l = (u16*)allocB(n * 2); };
  u16 *UtFh,*UtFl,*UtBh,*UtBl,*WtFh,*WtFl,*WtBh,*WtBl;
  u16 *dUth,*dUtl,*dWcth,*dWctl,*dWxth,*dWxtl;
  u16 *oWth,*oWtl,*aStth,*aSttl,*aSrth,*aSrtl;
  u16 *sEh,*sEl,*tEh,*tEl;
  planes2((size_t)G3*H_, UtFh, UtFl);   planes2((size_t)G3*H_, UtBh, UtBl);
  planes2((size_t)G3*D_, WtFh, WtFl);   planes2((size_t)G3*D_, WtBh, WtBl);
  planes2((size_t)G3*H_, dUth, dUtl);   planes2((size_t)G3*H_, dWcth, dWctl);
  planes2((size_t)G3*D_, dWxth, dWxtl);
  planes2((size_t)H_*VT_, oWth, oWtl);
  planes2((size_t)H_*H_, aSrth, aSrtl);
  planes2((size_t)H_*H_, aStth, aSttl);
  planes2((size_t)VT_*D_, sEh, sEl);    planes2((size_t)VT_*D_, tEh, tEl);
  float* Tf = (float*)allocB((size_t)VT_ * G3 * 4);
  float* Tb = (float*)allocB((size_t)VT_ * G3 * 4);
  float* Td = (float*)allocB((size_t)VT_ * G3 * 4);

  TPack P;
  P.m[0] = { enc_f_U,          UtFh, UtFl, 256, 768, 0   };
  P.m[1] = { enc_b_U,          UtBh, UtBl, 256, 768, 48  };
  P.m[2] = { dec_U,            dUth, dUtl, 256, 768, 96  };
  P.m[3] = { dec_W + 128 * G3, dWcth, dWctl, 256, 768, 144 };
  P.m[4] = { enc_f_W,          WtFh, WtFl, 128, 768, 192 };
  P.m[5] = { enc_b_W,          WtBh, WtBl, 128, 768, 216 };
  P.m[6] = { dec_W,            dWxth, dWxtl, 128, 768, 240 };
  P.m[7] = { out_W,            oWth, oWtl, 256, 256, 264 };
  P.m[8] = { att_src_W,        aSrth, aSrtl, 256, 256, 280 };
  P.m[9] = { att_st_W,         aStth, aSttl, 256, 256, 296 };
  wsplit_t<<<312, 256, 0, stream>>>(P);
  esplit<<<(2 * VT_ * D_ + 255) / 256, 256, 0, stream>>>(src_emb, tgt_emb, sEh, sEl, tEh, tEl, VT_ * D_);

  // ---- gx tables: emb @ W (split-bf16 3-pass, f32 out) ----
  {
    PLeg tf = { sEh, sEl, D_, WtFh, WtFl, D_, nullptr, Tf, G3, 0, VT_, G3, D_ };
    PLeg tb = { sEh, sEl, D_, WtBh, WtBl, D_, nullptr, Tb, G3, 0, VT_, G3, D_ };
    gemm_pl<<<dim3(6, 2, 2), 256, 0, stream>>>(tf, tb);
    PLeg td = { tEh, tEl, D_, dWxth, dWxtl, D_, nullptr, Td, G3, 0, VT_, G3, D_ };
    gemm_pl<<<dim3(6, 2, 1), 256, 0, stream>>>(td, td);
  }

  hipMemsetAsync(encF0, 0, 2 * BH * 4, stream);
  hipMemsetAsync(encPl0, 0, 4 * BH * 2, stream);

  // ---- encoder ----
  for (int s = 0; s < S_; s++) {
    int p = s & 1;
    GruDesc dd[2];
    for (int d = 0; d < 2; d++) {
      GruDesc& D = dd[d];
      D.a0H = encH[p][d]; D.a0L = encL[p][d];
      D.a1H = nullptr; D.a1L = nullptr;
      D.b0H = d ? UtBh : UtFh; D.b0L = d ? UtBl : UtFl;
      D.b1H = nullptr; D.b1L = nullptr;
      D.gxT = d ? Tb : Tf;
      D.bias0 = d ? enc_b_b : enc_f_b;
      D.bias1 = (d ? enc_b_b : enc_f_b) + G3;
      D.hold = encF[p][d]; D.holdH = nullptr; D.holdL = nullptr;
      D.hnew = encF[p ^ 1][d];
      D.hh = encH[p ^ 1][d]; D.hl = encL[p ^ 1][d];
      int pos = d ? (S_ - 1 - s) : s;
      D.ssH = ssH + (size_t)pos * BH; D.ssL = ssL + (size_t)pos * BH;
      D.ids = source_ids;
      D.ssmode = (s < S_ / 2) ? 1 : 2;
      D.sidx = s; D.rev = d;
    }
    gru_step<0><<<dim3(4, 64, 2), 256, 0, stream>>>(dd[0], dd[1]);
  }

  // ---- proj (bf16) + p0 (f32) ----
  {
    PLeg proj = { ssH, ssL, H_, aSrth, aSrtl, H_, att_src_b, projbf, H_, 1, S_ * B_, H_, H_ };
    PLeg p0   = { ssH, ssL, H_, aStth, aSttl, H_, att_st_b,  pbuf,   H_, 0, B_,      H_, H_ };
    gemm_pl<<<dim3(2, 512, 2), 256, 0, stream>>>(proj, p0);
  }
  attend_k<<<B_, 256, 0, stream>>>(projbf, ssH, pbuf, att_v, ctxh, ctxl);

  // ---- decoder ----
  for (int t = 0; t < T_; t++) {
    int p = t & 1;
    GruDesc D = {};
    D.a0H = t ? hAllH + (size_t)(t - 1) * BH : ssH;
    D.a0L = t ? hAllL + (size_t)(t - 1) * BH : ssL;
    D.a1H = ctxh; D.a1L = ctxl;
    D.b0H = dUth;  D.b0L = dUtl;
    D.b1H = dWcth; D.b1L = dWctl;
    D.gxT = Td;
    D.bias0 = dec_b; D.bias1 = dec_b + G3;
    if (t == 0) { D.hold = nullptr; D.holdH = ssH; D.holdL = ssL; }
    else        { D.hold = hDecF[p]; D.holdH = nullptr; D.holdL = nullptr; }
    D.hnew = hDecF[p ^ 1];
    D.hh = hAllH + (size_t)t * BH; D.hl = hAllL + (size_t)t * BH;
    D.ssH = nullptr; D.ssL = nullptr;
    D.ids = target_ids;
    D.ssmode = 0; D.sidx = t; D.rev = 0;
    gru_step<1><<<dim3(8, 64, 1), 256, 0, stream>>>(D, D);

    if (t < T_ - 1) {
      PLeg LP = { hAllH + (size_t)t * BH, hAllL + (size_t)t * BH, H_,
                  aStth, aSttl, H_, att_st_b, pbuf, H_, 0, B_, H_, H_ };
      gemm_pl<<<dim3(2, 16, 1), 256, 0, stream>>>(LP, LP);
      attend_k<<<B_, 256, 0, stream>>>(projbf, ssH, pbuf, att_v, ctxh, ctxl);
    }
  }

  // ---- batched logits ----
  {
    PLeg LO = { hAllH, hAllL, H_, oWth, oWtl, H_, out_b, out, 0, 2, T_ * B_, VT_, H_ };
    gemm_pl<<<dim3(2, 512, 1), 256, 0, stream>>>(LO, LO);
  }
}